// Round 18
// baseline (2904.742 us; speedup 1.0000x reference)
//
#include <hip/hip_runtime.h>
#include <stdint.h>

#define Bsz 4096
#define Tsz 24
#define Isz 128
#define Hsz 512
#define Wsz 32
#define Msz (Bsz * Tsz)   // 98304 flat rows (b*T+t)

typedef __attribute__((ext_vector_type(8))) short short8;
typedef __attribute__((ext_vector_type(4))) float f32x4;
typedef unsigned short u16;

__device__ __forceinline__ float bf2f(u16 u) {
    union { unsigned int i; float f; } v; v.i = ((unsigned int)u) << 16; return v.f;
}
__device__ __forceinline__ u16 f2bf(float f) {
    union { float f; unsigned int i; } v; v.f = f;
    unsigned int r = v.i + 0x7fffu + ((v.i >> 16) & 1u);
    return (u16)(r >> 16);
}
__device__ __forceinline__ float sigm(float x) { return 1.0f / (1.0f + expf(-x)); }

__device__ __forceinline__ f32x4 MF(short8 a, short8 b, f32x4 c) {
    return __builtin_amdgcn_mfma_f32_16x16x32_bf16(a, b, c, 0, 0, 0);
}
__device__ __forceinline__ short8 ntload8(const u16* p) {
    return __builtin_nontemporal_load((const short8*)p);
}

#define GLOAD_LDS16(SRC, DST) \
    __builtin_amdgcn_global_load_lds( \
        (__attribute__((address_space(1))) void*)(SRC), \
        (__attribute__((address_space(3))) void*)(DST), 16, 0, 0)

// ---------------- f32 -> bf16 conversion ----------------------------------
__global__ __launch_bounds__(256) void convert_big(
    const float* __restrict__ src, u16* __restrict__ dst, int n)
{
    int i = (blockIdx.x * 256 + threadIdx.x) * 4;
    if (i + 4 <= n) {
        float4 v = *(const float4*)(src + i);
        dst[i + 0] = f2bf(v.x); dst[i + 1] = f2bf(v.y);
        dst[i + 2] = f2bf(v.z); dst[i + 3] = f2bf(v.w);
    }
}

struct ConvDesc { const float* src; u16* dst; int n; };
struct ConvTab { ConvDesc d[13]; };

__global__ __launch_bounds__(256) void convert_many(ConvTab tab)
{
    ConvDesc cd = tab.d[blockIdx.y];
    for (int i = (blockIdx.x * 256 + threadIdx.x) * 4; i < cd.n;
         i += gridDim.x * 256 * 4) {
        float4 v = *(const float4*)(cd.src + i);
        cd.dst[i + 0] = f2bf(v.x); cd.dst[i + 1] = f2bf(v.y);
        cd.dst[i + 2] = f2bf(v.z); cd.dst[i + 3] = f2bf(v.w);
    }
}

// ======================= prepass GEMM machinery (r17-exact) =================
struct Seg { const u16* A; int astr; int shift; const u16* W; int wstr; int nkb; };

__device__ __forceinline__ void stage_half(
    u16* ldsT, const u16* gbase, int rstr, int rvf,
    const u16* zerobuf, int wid, int lane)
{
#pragma unroll
    for (int q = 0; q < 4; ++q) {
        int c   = wid * 4 + q;
        int lin = c * 64 + lane;
        int row = lin >> 3;
        int gc  = lin & 7;
        const u16* src = (row >= rvf)
            ? (gbase + (long)row * rstr + ((gc ^ (row & 7)) << 3))
            : zerobuf;
        GLOAD_LDS16(src, ldsT + c * 512);
    }
}

__device__ __forceinline__ void stage_step(
    const Seg* segs, int nseg, int kb, u16* ldsA, u16* ldsB,
    int m0, int n0, const u16* zerobuf, int wid, int lane)
{
    Seg s = segs[0];
    int kloc = kb;
    if (nseg > 1 && kloc >= s.nkb) {
        kloc -= s.nkb; s = segs[1];
        if (nseg > 2 && kloc >= s.nkb) { kloc -= s.nkb; s = segs[2]; }
    }
    int base_row = m0 + s.shift;
    int rvf = base_row < 0 ? -base_row : 0;
    stage_half(ldsA, s.A + (long)base_row * s.astr + kloc * 64, s.astr, rvf,
               zerobuf, wid, lane);
    stage_half(ldsB, s.W + (long)n0 * s.wstr + kloc * 64, s.wstr, 0,
               zerobuf, wid, lane);
}

__device__ __forceinline__ void compute_tile(
    f32x4 acc[4][4], const u16* Ab, const u16* Bb, int wr, int wc, int lane)
{
    const int l15 = lane & 15;
    const int hi = lane >> 4;
#pragma unroll
    for (int ks = 0; ks < 2; ++ks) {
        int kg = ks * 4 + hi;
        short8 a[4], b[4];
#pragma unroll
        for (int am = 0; am < 4; ++am) {
            int row = wr * 64 + am * 16 + l15;
            a[am] = *(const short8*)(Ab + row * 64 + ((kg ^ (row & 7)) << 3));
        }
#pragma unroll
        for (int bn = 0; bn < 4; ++bn) {
            int row = wc * 64 + bn * 16 + l15;
            b[bn] = *(const short8*)(Bb + row * 64 + ((kg ^ (row & 7)) << 3));
        }
#pragma unroll
        for (int am = 0; am < 4; ++am)
#pragma unroll
            for (int bn = 0; bn < 4; ++bn)
                acc[am][bn] = MF(a[am], b[bn], acc[am][bn]);
    }
}

#define GEMM_CORE(SEGS, NSEG, M0, N0W)                                          \
    __shared__ u16 lds[2][2][128 * 64];                                         \
    const int lane = threadIdx.x & 63;                                          \
    const int wid  = threadIdx.x >> 6;                                          \
    const int wr = wid >> 1, wc = wid & 1;                                      \
    f32x4 acc[4][4];                                                            \
    _Pragma("unroll") for (int i_ = 0; i_ < 4; ++i_)                            \
    _Pragma("unroll") for (int j_ = 0; j_ < 4; ++j_)                            \
        acc[i_][j_] = f32x4{0, 0, 0, 0};                                        \
    int nkb = 0;                                                                \
    for (int s_ = 0; s_ < (NSEG); ++s_) nkb += (SEGS)[s_].nkb;                  \
    stage_step((SEGS), (NSEG), 0, lds[0][0], lds[0][1], (M0), (N0W),            \
               zerobuf, wid, lane);                                             \
    int cur = 0;                                                                \
    for (int kb = 0; kb < nkb; ++kb) {                                          \
        __syncthreads();                                                        \
        if (kb + 1 < nkb)                                                       \
            stage_step((SEGS), (NSEG), kb + 1, lds[cur ^ 1][0],                 \
                       lds[cur ^ 1][1], (M0), (N0W), zerobuf, wid, lane);       \
        compute_tile(acc, lds[cur][0], lds[cur][1], wr, wc, lane);              \
        cur ^= 1;                                                               \
    }

// ---------------- e = sigmoid(xw @ w_e^T + b_e), e layout [b*T+t][512] -----
__global__ __launch_bounds__(256) void ekernel(
    const u16* __restrict__ xw, const u16* __restrict__ w_e,
    const float* __restrict__ b_e, u16* __restrict__ eout)
{
    const int lane = threadIdx.x & 63;
    const int wid  = threadIdx.x >> 6;
    const int m0 = blockIdx.x * 64 + (wid >> 1) * 32;
    const int n0 = blockIdx.y * 64 + (wid & 1) * 32;
    f32x4 acc[2][2];
    acc[0][0] = f32x4{0,0,0,0}; acc[0][1] = f32x4{0,0,0,0};
    acc[1][0] = f32x4{0,0,0,0}; acc[1][1] = f32x4{0,0,0,0};
    const int l15 = lane & 15;
    const int klane = (lane >> 4) * 8;
    short8 b0 = *(const short8*)(w_e + (n0 + l15) * Wsz + klane);
    short8 b1 = *(const short8*)(w_e + (n0 + 16 + l15) * Wsz + klane);
#pragma unroll
    for (int am = 0; am < 2; ++am) {
        short8 a = *(const short8*)(xw + (long)(m0 + am * 16 + l15) * Wsz + klane);
        acc[am][0] = MF(a, b0, acc[am][0]);
        acc[am][1] = MF(a, b1, acc[am][1]);
    }
    const int col = lane & 15;
    const int r0 = (lane >> 4) * 4;
#pragma unroll
    for (int am = 0; am < 2; ++am)
#pragma unroll
        for (int bn = 0; bn < 2; ++bn)
#pragma unroll
            for (int i = 0; i < 4; ++i) {
                long row = m0 + am * 16 + r0 + i;
                int g = n0 + bn * 16 + col;
                eout[row * Hsz + g] = f2bf(sigm(acc[am][bn][i] + b_e[g]));
            }
}

// ---------------- pre-pass (r17-exact; XCD-stream block swizzle) ------------
__global__ __launch_bounds__(256, 2) void prepass_kernel(
    const u16* __restrict__ x, const u16* __restrict__ e,
    const u16* __restrict__ w_d, const u16* __restrict__ w_w,
    const u16* __restrict__ w_m, const u16* __restrict__ w_rx,
    const u16* __restrict__ w_re, const u16* __restrict__ w_zx,
    const u16* __restrict__ w_ze, const u16* __restrict__ w_hx,
    const float* __restrict__ b_r, const float* __restrict__ b_z,
    const float* __restrict__ b_h,
    const u16* __restrict__ zerobuf, u16* __restrict__ prep)
{
    const int p = blockIdx.x;
    const int xcd = p & 7, q = p >> 3;
    const int mblk = xcd + 8 * (q >> 4);   // 0..767
    const int yy = q & 15;
    const int m0 = mblk * 128;
    const int group = yy >> 2;
    const int nin = (yy & 3) * 128;
    Seg segs[3];
    int nseg;
    const float* bias = nullptr;
    if (group == 0) {
        segs[0] = { x, Isz, -1 * Tsz,  w_d, Isz, Isz / 64 };
        segs[1] = { x, Isz, -7 * Tsz,  w_w, Isz, Isz / 64 };
        segs[2] = { x, Isz, -30 * Tsz, w_m, Isz, Isz / 64 };
        nseg = 3;
    } else if (group == 1) {
        segs[0] = { x, Isz, 0, w_rx, Isz, Isz / 64 };
        segs[1] = { e, Hsz, 0, w_re, Hsz, Hsz / 64 };
        nseg = 2; bias = b_r;
    } else if (group == 2) {
        segs[0] = { x, Isz, 0, w_zx, Isz, Isz / 64 };
        segs[1] = { e, Hsz, 0, w_ze, Hsz, Hsz / 64 };
        nseg = 2; bias = b_z;
    } else {
        segs[0] = { x, Isz, 0, w_hx, Isz, Isz / 64 };
        nseg = 1; bias = b_h;
    }
    GEMM_CORE(segs, nseg, m0, nin)
    const int l15 = lane & 15, hi4v = (lane >> 4) * 4;
#pragma unroll
    for (int am = 0; am < 4; ++am)
#pragma unroll
        for (int bn = 0; bn < 4; ++bn) {
            int colH = nin + wc * 64 + bn * 16 + l15;
            float bv = bias ? bias[colH] : 0.0f;
            int wv = colH >> 5, ntv = (colH >> 4) & 1, l15v = colH & 15;
#pragma unroll
            for (int i = 0; i < 4; ++i) {
                long m = m0 + wr * 64 + am * 16 + hi4v + i;
                int b = (int)(m / Tsz), t = (int)(m % Tsz);
                int bblk = b >> 4, rowin = b & 15;
                int hiv = rowin >> 2, iv = rowin & 3;
                long idx = (((long)(bblk * Tsz + t) * 4 + group) * 16 + wv) * 512
                           + (hiv * 16 + l15v) * 8 + ntv * 4 + iv;
                prep[idx] = f2bf(acc[am][bn][i] + bv);
            }
        }
}

// ======================= persistent recurrence ==============================
// r17 structure; the chunk loop is now FULLY UNROLLED so c/kk are
// compile-time: global_load_lds source addresses and LDS read offsets fold
// to base+immediate (VALUBusy was 30% of the kernel at unroll 1).
#define SROW 528

__device__ __forceinline__ int swz(int row, int col) {
    return row * SROW + ((((col >> 3) ^ (row & 7)) << 3) | (col & 7));
}

__device__ __forceinline__ void stage_chunk64(
    const u16* __restrict__ Wm, int c, u16* buf, int wave, int lane)
{
    int s1 = wave * 128 + lane;
    int s2 = s1 + 64;
    int p1 = s1 >> 3, g1 = (s1 & 7) ^ (p1 & 7);
    int p2 = s2 >> 3, g2 = (s2 & 7) ^ (p2 & 7);
#pragma unroll
    for (int h = 0; h < 2; ++h) {
        GLOAD_LDS16(Wm + (long)(2 * p1 + (g1 >> 2)) * 512
                       + c * 64 + h * 32 + (g1 & 3) * 8,
                    buf + h * 16384 + wave * 1024);
        GLOAD_LDS16(Wm + (long)(2 * p2 + (g2 >> 2)) * 512
                       + c * 64 + h * 32 + (g2 & 3) * 8,
                    buf + h * 16384 + wave * 1024 + 512);
    }
}

__device__ __forceinline__ void wpass_staged(
    f32x4 acc[2], const u16* aS, const u16* __restrict__ Wm,
    u16* wbuf0, u16* wbuf1, int bo0, int rx, int l15, int hi,
    int wave, int lane)
{
    const u16* ap = aS + l15 * SROW;
    stage_chunk64(Wm, 0, wbuf0, wave, lane);
#pragma unroll
    for (int c = 0; c < 8; ++c) {
        __syncthreads();              // chunk c resident (vmcnt drain + bar)
        u16* cur = (c & 1) ? wbuf1 : wbuf0;
        u16* nxt = (c & 1) ? wbuf0 : wbuf1;
        if (c < 7) stage_chunk64(Wm, c + 1, nxt, wave, lane);
#pragma unroll
        for (int kk = 0; kk < 2; ++kk) {
            short8 b0 = *(const short8*)(cur + kk * 16384 + bo0);
            short8 b1 = *(const short8*)(cur + kk * 16384 + bo0 + 512);
            short8 a = *(const short8*)(
                ap + ((((c * 2 + kk) * 4 + hi) ^ rx) << 3));
            acc[0] = MF(a, b0, acc[0]);
            acc[1] = MF(a, b1, acc[1]);
        }
    }
}

#define FOR_FRAG \
    _Pragma("unroll") for (int nt2 = 0; nt2 < 2; ++nt2) \
    _Pragma("unroll") for (int i = 0; i < 4; ++i)

__global__ __launch_bounds__(1024, 4) void rnn_kernel(
    const u16* __restrict__ prep, const u16* __restrict__ w_t_,
    const u16* __restrict__ w_rh, const u16* __restrict__ w_zh,
    const u16* __restrict__ w_hh, float* __restrict__ out)
{
    __shared__ __align__(16) u16 hS[16 * SROW];        // h / ho / rh
    __shared__ __align__(16) u16 wbuf0[32 * 1024];     // 64KB chunk buf A
    __shared__ __align__(16) u16 wbuf1[32 * 1024];     // 64KB chunk buf B
    const int tid = threadIdx.x;
    const int lane = tid & 63;
    const int wave = tid >> 6;
    const int l15 = lane & 15, hi = lane >> 4;
    const int rx = l15 & 7;
    const int n0 = wave * 32;
    const long b0 = (long)blockIdx.x * 16;
    const int bo0 = (wave * 128 + (l15 >> 1) * 8
                     + ((hi + 4 * (l15 & 1)) ^ (l15 >> 1))) * 8;

    for (int i = tid * 8; i < 16 * SROW; i += 1024 * 8)
        *(short8*)(hS + i) = (short8)0;
    __syncthreads();

    const u16* pbase = prep + (long)blockIdx.x * (Tsz * 4 * 8192)
                       + wave * 512 + lane * 8;

#pragma unroll 1
    for (int t = 0; t < Tsz; ++t) {
        const u16* pt = pbase + (long)t * 4 * 8192;
        short8 po = ntload8(pt);

        // ---- stage A: ho = sigm(pre_o + h @ w_t^T)  [reads hS = h] ----
        f32x4 accO[2];
        accO[0] = f32x4{0,0,0,0}; accO[1] = f32x4{0,0,0,0};
        wpass_staged(accO, hS, w_t_, wbuf0, wbuf1, bo0, rx, l15, hi,
                     wave, lane);
        float hov[2][4];
        FOR_FRAG {
            float v = sigm(accO[nt2][i] + bf2f((u16)po[nt2 * 4 + i]));
            hov[nt2][i] = v;
        }
        __syncthreads();   // all waves done reading hS(=h)
        FOR_FRAG hS[swz(hi * 4 + i, n0 + nt2 * 16 + l15)] = f2bf(hov[nt2][i]);

        // ---- stage B: r,z = sigm(pre + ho @ w^T)  [reads hS = ho] ----
        short8 pr = ntload8(pt + 8192);
        short8 pz = ntload8(pt + 2 * 8192);
        f32x4 accR[2];
        accR[0] = f32x4{0,0,0,0}; accR[1] = f32x4{0,0,0,0};
        wpass_staged(accR, hS, w_rh, wbuf0, wbuf1, bo0, rx, l15, hi,
                     wave, lane);
        f32x4 accZ[2];
        accZ[0] = f32x4{0,0,0,0}; accZ[1] = f32x4{0,0,0,0};
        wpass_staged(accZ, hS, w_zh, wbuf0, wbuf1, bo0, rx, l15, hi,
                     wave, lane);
        float zv[2][4], rhv[2][4];
        FOR_FRAG {
            zv[nt2][i] = sigm(accZ[nt2][i] + bf2f((u16)pz[nt2 * 4 + i]));
            float rv = sigm(accR[nt2][i] + bf2f((u16)pr[nt2 * 4 + i]));
            rhv[nt2][i] = rv * hov[nt2][i];
        }
        __syncthreads();   // all waves done reading hS(=ho)
        FOR_FRAG hS[swz(hi * 4 + i, n0 + nt2 * 16 + l15)] = f2bf(rhv[nt2][i]);

        // ---- stage C: h~ = tanh(pre_h + rh @ w_hh^T)  [reads hS = rh] ----
        short8 ph = ntload8(pt + 3 * 8192);
        f32x4 accH[2];
        accH[0] = f32x4{0,0,0,0}; accH[1] = f32x4{0,0,0,0};
        wpass_staged(accH, hS, w_hh, wbuf0, wbuf1, bo0, rx, l15, hi,
                     wave, lane);
        __syncthreads();   // all waves done reading hS(=rh)
        FOR_FRAG {
            int row = hi * 4 + i, col = n0 + nt2 * 16 + l15;
            float htl = tanhf(accH[nt2][i] + bf2f((u16)ph[nt2 * 4 + i]));
            float z = zv[nt2][i];
            float hn = (1.0f - z) * hov[nt2][i] + z * htl;
            __builtin_nontemporal_store(
                hn, &out[((b0 + row) * Tsz + t) * (long)Hsz + col]);
            hS[swz(row, col)] = f2bf(hn);
        }
    }
}

extern "C" void kernel_launch(void* const* d_in, const int* in_sizes, int n_in,
                              void* d_out, int out_size, void* d_ws, size_t ws_size,
                              hipStream_t stream) {
    const float* x_f    = (const float*)d_in[0];
    const float* xw_f   = (const float*)d_in[1];
    const float* w_rx_f = (const float*)d_in[2];
    const float* w_rh_f = (const float*)d_in[3];
    const float* w_re_f = (const float*)d_in[4];
    const float* b_r    = (const float*)d_in[5];
    const float* w_zx_f = (const float*)d_in[6];
    const float* w_zh_f = (const float*)d_in[7];
    const float* w_ze_f = (const float*)d_in[8];
    const float* b_z    = (const float*)d_in[9];
    const float* w_hx_f = (const float*)d_in[10];
    const float* w_hh_f = (const float*)d_in[11];
    const float* b_h    = (const float*)d_in[12];
    const float* w_d_f  = (const float*)d_in[13];
    const float* w_w_f  = (const float*)d_in[14];
    const float* w_m_f  = (const float*)d_in[15];
    const float* w_t_f  = (const float*)d_in[16];
    const float* w_e_f  = (const float*)d_in[17];
    const float* b_e    = (const float*)d_in[18];
    float* out = (float*)d_out;

    char* ws = (char*)d_ws;
    size_t off = 0;
    auto alloc = [&](size_t bytes) {
        size_t o = off; off = (off + bytes + 255) & ~(size_t)255; return o;
    };
    const size_t nx  = (size_t)Msz * Isz;
    const size_t nxw = (size_t)Msz * Wsz;

    u16* x_bf  = (u16*)(ws + alloc(nx * 2));
    u16* xw_bf = (u16*)(ws + alloc(nxw * 2));
    u16* w_rx  = (u16*)(ws + alloc(Hsz * Isz * 2));
    u16* w_rh  = (u16*)(ws + alloc(Hsz * Hsz * 2));
    u16* w_re  = (u16*)(ws + alloc(Hsz * Hsz * 2));
    u16* w_zx  = (u16*)(ws + alloc(Hsz * Isz * 2));
    u16* w_zh  = (u16*)(ws + alloc(Hsz * Hsz * 2));
    u16* w_ze  = (u16*)(ws + alloc(Hsz * Hsz * 2));
    u16* w_hx  = (u16*)(ws + alloc(Hsz * Isz * 2));
    u16* w_hh  = (u16*)(ws + alloc(Hsz * Hsz * 2));
    u16* w_d   = (u16*)(ws + alloc(Hsz * Isz * 2));
    u16* w_w   = (u16*)(ws + alloc(Hsz * Isz * 2));
    u16* w_m   = (u16*)(ws + alloc(Hsz * Isz * 2));
    u16* w_t   = (u16*)(ws + alloc(Hsz * Hsz * 2));
    u16* w_e   = (u16*)(ws + alloc(Hsz * Wsz * 2));
    u16* e_bf  = (u16*)(ws + alloc((size_t)Msz * Hsz * 2));   // 96 MB [b*T+t]
    u16* prep  = (u16*)(ws + alloc((size_t)Msz * 2048 * 2));  // 384 MB permuted
    u16* zerobuf = (u16*)(ws + alloc(256));

    convert_big<<<(int)(nx / 1024), 256, 0, stream>>>(x_f, x_bf, (int)nx);
    convert_big<<<(int)(nxw / 1024), 256, 0, stream>>>(xw_f, xw_bf, (int)nxw);
    ConvTab tab;
    tab.d[0]  = { w_rx_f, w_rx, Hsz * Isz };
    tab.d[1]  = { w_rh_f, w_rh, Hsz * Hsz };
    tab.d[2]  = { w_re_f, w_re, Hsz * Hsz };
    tab.d[3]  = { w_zx_f, w_zx, Hsz * Isz };
    tab.d[4]  = { w_zh_f, w_zh, Hsz * Hsz };
    tab.d[5]  = { w_ze_f, w_ze, Hsz * Hsz };
    tab.d[6]  = { w_hx_f, w_hx, Hsz * Isz };
    tab.d[7]  = { w_hh_f, w_hh, Hsz * Hsz };
    tab.d[8]  = { w_d_f,  w_d,  Hsz * Isz };
    tab.d[9]  = { w_w_f,  w_w,  Hsz * Isz };
    tab.d[10] = { w_m_f,  w_m,  Hsz * Isz };
    tab.d[11] = { w_t_f,  w_t,  Hsz * Hsz };
    tab.d[12] = { w_e_f,  w_e,  Hsz * Wsz };
    convert_many<<<dim3(256, 13), 256, 0, stream>>>(tab);
    hipMemsetAsync(zerobuf, 0, 256, stream);

    // e = sigmoid(xw @ w_e^T + b_e)  [98304 x 512], layout [b*T+t]
    ekernel<<<dim3(Msz / 64, Hsz / 64), 256, 0, stream>>>(xw_bf, w_e, b_e, e_bf);

    // pre-pass: 1-D grid, XCD-stream swizzle
    prepass_kernel<<<Msz / 128 * 16, 256, 0, stream>>>(
        x_bf, e_bf, w_d, w_w, w_m, w_rx, w_re, w_zx, w_ze, w_hx,
        b_r, b_z, b_h, zerobuf, prep);

    // persistent recurrence: 256 blocks x 16 waves, K=64 staged chunks,
    // fully-unrolled chunk loop (compile-time addresses)
    rnn_kernel<<<Bsz / 16, 1024, 0, stream>>>(prep, w_t, w_rh, w_zh, w_hh, out);
}

// Round 19
// 1529.946 us; speedup vs baseline: 1.8986x; 1.8986x over previous
//
#include <hip/hip_runtime.h>
#include <stdint.h>

#define Bsz 4096
#define Tsz 24
#define Isz 128
#define Hsz 512
#define Wsz 32
#define Msz (Bsz * Tsz)   // 98304 flat rows (b*T+t)

typedef __attribute__((ext_vector_type(8))) short short8;
typedef __attribute__((ext_vector_type(4))) float f32x4;
typedef unsigned short u16;

__device__ __forceinline__ float bf2f(u16 u) {
    union { unsigned int i; float f; } v; v.i = ((unsigned int)u) << 16; return v.f;
}
__device__ __forceinline__ u16 f2bf(float f) {
    union { float f; unsigned int i; } v; v.f = f;
    unsigned int r = v.i + 0x7fffu + ((v.i >> 16) & 1u);
    return (u16)(r >> 16);
}
__device__ __forceinline__ float sigm(float x) { return 1.0f / (1.0f + expf(-x)); }

__device__ __forceinline__ f32x4 MF(short8 a, short8 b, f32x4 c) {
    return __builtin_amdgcn_mfma_f32_16x16x32_bf16(a, b, c, 0, 0, 0);
}
__device__ __forceinline__ short8 ntload8(const u16* p) {
    return __builtin_nontemporal_load((const short8*)p);
}

#define GLOAD_LDS16(SRC, DST) \
    __builtin_amdgcn_global_load_lds( \
        (__attribute__((address_space(1))) void*)(SRC), \
        (__attribute__((address_space(3))) void*)(DST), 16, 0, 0)

// ---------------- f32 -> bf16 conversion ----------------------------------
__global__ __launch_bounds__(256) void convert_big(
    const float* __restrict__ src, u16* __restrict__ dst, int n)
{
    int i = (blockIdx.x * 256 + threadIdx.x) * 4;
    if (i + 4 <= n) {
        float4 v = *(const float4*)(src + i);
        dst[i + 0] = f2bf(v.x); dst[i + 1] = f2bf(v.y);
        dst[i + 2] = f2bf(v.z); dst[i + 3] = f2bf(v.w);
    }
}

struct ConvDesc { const float* src; u16* dst; int n; };
struct ConvTab { ConvDesc d[13]; };

__global__ __launch_bounds__(256) void convert_many(ConvTab tab)
{
    ConvDesc cd = tab.d[blockIdx.y];
    for (int i = (blockIdx.x * 256 + threadIdx.x) * 4; i < cd.n;
         i += gridDim.x * 256 * 4) {
        float4 v = *(const float4*)(cd.src + i);
        cd.dst[i + 0] = f2bf(v.x); cd.dst[i + 1] = f2bf(v.y);
        cd.dst[i + 2] = f2bf(v.z); cd.dst[i + 3] = f2bf(v.w);
    }
}

// ======================= prepass GEMM machinery (r17-exact) =================
struct Seg { const u16* A; int astr; int shift; const u16* W; int wstr; int nkb; };

__device__ __forceinline__ void stage_half(
    u16* ldsT, const u16* gbase, int rstr, int rvf,
    const u16* zerobuf, int wid, int lane)
{
#pragma unroll
    for (int q = 0; q < 4; ++q) {
        int c   = wid * 4 + q;
        int lin = c * 64 + lane;
        int row = lin >> 3;
        int gc  = lin & 7;
        const u16* src = (row >= rvf)
            ? (gbase + (long)row * rstr + ((gc ^ (row & 7)) << 3))
            : zerobuf;
        GLOAD_LDS16(src, ldsT + c * 512);
    }
}

__device__ __forceinline__ void stage_step(
    const Seg* segs, int nseg, int kb, u16* ldsA, u16* ldsB,
    int m0, int n0, const u16* zerobuf, int wid, int lane)
{
    Seg s = segs[0];
    int kloc = kb;
    if (nseg > 1 && kloc >= s.nkb) {
        kloc -= s.nkb; s = segs[1];
        if (nseg > 2 && kloc >= s.nkb) { kloc -= s.nkb; s = segs[2]; }
    }
    int base_row = m0 + s.shift;
    int rvf = base_row < 0 ? -base_row : 0;
    stage_half(ldsA, s.A + (long)base_row * s.astr + kloc * 64, s.astr, rvf,
               zerobuf, wid, lane);
    stage_half(ldsB, s.W + (long)n0 * s.wstr + kloc * 64, s.wstr, 0,
               zerobuf, wid, lane);
}

__device__ __forceinline__ void compute_tile(
    f32x4 acc[4][4], const u16* Ab, const u16* Bb, int wr, int wc, int lane)
{
    const int l15 = lane & 15;
    const int hi = lane >> 4;
#pragma unroll
    for (int ks = 0; ks < 2; ++ks) {
        int kg = ks * 4 + hi;
        short8 a[4], b[4];
#pragma unroll
        for (int am = 0; am < 4; ++am) {
            int row = wr * 64 + am * 16 + l15;
            a[am] = *(const short8*)(Ab + row * 64 + ((kg ^ (row & 7)) << 3));
        }
#pragma unroll
        for (int bn = 0; bn < 4; ++bn) {
            int row = wc * 64 + bn * 16 + l15;
            b[bn] = *(const short8*)(Bb + row * 64 + ((kg ^ (row & 7)) << 3));
        }
#pragma unroll
        for (int am = 0; am < 4; ++am)
#pragma unroll
            for (int bn = 0; bn < 4; ++bn)
                acc[am][bn] = MF(a[am], b[bn], acc[am][bn]);
    }
}

#define GEMM_CORE(SEGS, NSEG, M0, N0W)                                          \
    __shared__ u16 lds[2][2][128 * 64];                                         \
    const int lane = threadIdx.x & 63;                                          \
    const int wid  = threadIdx.x >> 6;                                          \
    const int wr = wid >> 1, wc = wid & 1;                                      \
    f32x4 acc[4][4];                                                            \
    _Pragma("unroll") for (int i_ = 0; i_ < 4; ++i_)                            \
    _Pragma("unroll") for (int j_ = 0; j_ < 4; ++j_)                            \
        acc[i_][j_] = f32x4{0, 0, 0, 0};                                        \
    int nkb = 0;                                                                \
    for (int s_ = 0; s_ < (NSEG); ++s_) nkb += (SEGS)[s_].nkb;                  \
    stage_step((SEGS), (NSEG), 0, lds[0][0], lds[0][1], (M0), (N0W),            \
               zerobuf, wid, lane);                                             \
    int cur = 0;                                                                \
    for (int kb = 0; kb < nkb; ++kb) {                                          \
        __syncthreads();                                                        \
        if (kb + 1 < nkb)                                                       \
            stage_step((SEGS), (NSEG), kb + 1, lds[cur ^ 1][0],                 \
                       lds[cur ^ 1][1], (M0), (N0W), zerobuf, wid, lane);       \
        compute_tile(acc, lds[cur][0], lds[cur][1], wr, wc, lane);              \
        cur ^= 1;                                                               \
    }

// ---------------- e = sigmoid(xw @ w_e^T + b_e), e layout [b*T+t][512] -----
__global__ __launch_bounds__(256) void ekernel(
    const u16* __restrict__ xw, const u16* __restrict__ w_e,
    const float* __restrict__ b_e, u16* __restrict__ eout)
{
    const int lane = threadIdx.x & 63;
    const int wid  = threadIdx.x >> 6;
    const int m0 = blockIdx.x * 64 + (wid >> 1) * 32;
    const int n0 = blockIdx.y * 64 + (wid & 1) * 32;
    f32x4 acc[2][2];
    acc[0][0] = f32x4{0,0,0,0}; acc[0][1] = f32x4{0,0,0,0};
    acc[1][0] = f32x4{0,0,0,0}; acc[1][1] = f32x4{0,0,0,0};
    const int l15 = lane & 15;
    const int klane = (lane >> 4) * 8;
    short8 b0 = *(const short8*)(w_e + (n0 + l15) * Wsz + klane);
    short8 b1 = *(const short8*)(w_e + (n0 + 16 + l15) * Wsz + klane);
#pragma unroll
    for (int am = 0; am < 2; ++am) {
        short8 a = *(const short8*)(xw + (long)(m0 + am * 16 + l15) * Wsz + klane);
        acc[am][0] = MF(a, b0, acc[am][0]);
        acc[am][1] = MF(a, b1, acc[am][1]);
    }
    const int col = lane & 15;
    const int r0 = (lane >> 4) * 4;
#pragma unroll
    for (int am = 0; am < 2; ++am)
#pragma unroll
        for (int bn = 0; bn < 2; ++bn)
#pragma unroll
            for (int i = 0; i < 4; ++i) {
                long row = m0 + am * 16 + r0 + i;
                int g = n0 + bn * 16 + col;
                eout[row * Hsz + g] = f2bf(sigm(acc[am][bn][i] + b_e[g]));
            }
}

// ---------------- pre-pass (r17-exact; XCD-stream block swizzle) ------------
__global__ __launch_bounds__(256, 2) void prepass_kernel(
    const u16* __restrict__ x, const u16* __restrict__ e,
    const u16* __restrict__ w_d, const u16* __restrict__ w_w,
    const u16* __restrict__ w_m, const u16* __restrict__ w_rx,
    const u16* __restrict__ w_re, const u16* __restrict__ w_zx,
    const u16* __restrict__ w_ze, const u16* __restrict__ w_hx,
    const float* __restrict__ b_r, const float* __restrict__ b_z,
    const float* __restrict__ b_h,
    const u16* __restrict__ zerobuf, u16* __restrict__ prep)
{
    const int p = blockIdx.x;
    const int xcd = p & 7, q = p >> 3;
    const int mblk = xcd + 8 * (q >> 4);   // 0..767
    const int yy = q & 15;
    const int m0 = mblk * 128;
    const int group = yy >> 2;
    const int nin = (yy & 3) * 128;
    Seg segs[3];
    int nseg;
    const float* bias = nullptr;
    if (group == 0) {
        segs[0] = { x, Isz, -1 * Tsz,  w_d, Isz, Isz / 64 };
        segs[1] = { x, Isz, -7 * Tsz,  w_w, Isz, Isz / 64 };
        segs[2] = { x, Isz, -30 * Tsz, w_m, Isz, Isz / 64 };
        nseg = 3;
    } else if (group == 1) {
        segs[0] = { x, Isz, 0, w_rx, Isz, Isz / 64 };
        segs[1] = { e, Hsz, 0, w_re, Hsz, Hsz / 64 };
        nseg = 2; bias = b_r;
    } else if (group == 2) {
        segs[0] = { x, Isz, 0, w_zx, Isz, Isz / 64 };
        segs[1] = { e, Hsz, 0, w_ze, Hsz, Hsz / 64 };
        nseg = 2; bias = b_z;
    } else {
        segs[0] = { x, Isz, 0, w_hx, Isz, Isz / 64 };
        nseg = 1; bias = b_h;
    }
    GEMM_CORE(segs, nseg, m0, nin)
    const int l15 = lane & 15, hi4v = (lane >> 4) * 4;
#pragma unroll
    for (int am = 0; am < 4; ++am)
#pragma unroll
        for (int bn = 0; bn < 4; ++bn) {
            int colH = nin + wc * 64 + bn * 16 + l15;
            float bv = bias ? bias[colH] : 0.0f;
            int wv = colH >> 5, ntv = (colH >> 4) & 1, l15v = colH & 15;
#pragma unroll
            for (int i = 0; i < 4; ++i) {
                long m = m0 + wr * 64 + am * 16 + hi4v + i;
                int b = (int)(m / Tsz), t = (int)(m % Tsz);
                int bblk = b >> 4, rowin = b & 15;
                int hiv = rowin >> 2, iv = rowin & 3;
                long idx = (((long)(bblk * Tsz + t) * 4 + group) * 16 + wv) * 512
                           + (hiv * 16 + l15v) * 8 + ntv * 4 + iv;
                prep[idx] = f2bf(acc[am][bn][i] + bv);
            }
        }
}

// ======================= persistent recurrence (r17-exact) ==================
// NOTE: 1024-thread block = 16 waves = 4 waves/SIMD => hard 64-VGPR cap.
// Chunk loop stays at unroll 1: any schedule needing >64 live VGPRs
// (r18 full unroll, r10 manual prefetch) spills to scratch by construction.
#define SROW 528

__device__ __forceinline__ int swz(int row, int col) {
    return row * SROW + ((((col >> 3) ^ (row & 7)) << 3) | (col & 7));
}

__device__ __forceinline__ void stage_chunk64(
    const u16* __restrict__ Wm, int c, u16* buf, int wave, int lane)
{
    int s1 = wave * 128 + lane;
    int s2 = s1 + 64;
    int p1 = s1 >> 3, g1 = (s1 & 7) ^ (p1 & 7);
    int p2 = s2 >> 3, g2 = (s2 & 7) ^ (p2 & 7);
#pragma unroll
    for (int h = 0; h < 2; ++h) {
        GLOAD_LDS16(Wm + (long)(2 * p1 + (g1 >> 2)) * 512
                       + c * 64 + h * 32 + (g1 & 3) * 8,
                    buf + h * 16384 + wave * 1024);
        GLOAD_LDS16(Wm + (long)(2 * p2 + (g2 >> 2)) * 512
                       + c * 64 + h * 32 + (g2 & 3) * 8,
                    buf + h * 16384 + wave * 1024 + 512);
    }
}

__device__ __forceinline__ void wpass_staged(
    f32x4 acc[2], const u16* aS, const u16* __restrict__ Wm,
    u16* wbuf0, u16* wbuf1, int bo0, int rx, int l15, int hi,
    int wave, int lane)
{
    const u16* ap = aS + l15 * SROW;
    stage_chunk64(Wm, 0, wbuf0, wave, lane);
#pragma unroll 1
    for (int c = 0; c < 8; ++c) {
        __syncthreads();              // chunk c resident (vmcnt drain + bar)
        u16* cur = (c & 1) ? wbuf1 : wbuf0;
        u16* nxt = (c & 1) ? wbuf0 : wbuf1;
        if (c < 7) stage_chunk64(Wm, c + 1, nxt, wave, lane);
#pragma unroll
        for (int kk = 0; kk < 2; ++kk) {
            short8 b0 = *(const short8*)(cur + kk * 16384 + bo0);
            short8 b1 = *(const short8*)(cur + kk * 16384 + bo0 + 512);
            short8 a = *(const short8*)(
                ap + ((((c * 2 + kk) * 4 + hi) ^ rx) << 3));
            acc[0] = MF(a, b0, acc[0]);
            acc[1] = MF(a, b1, acc[1]);
        }
    }
}

#define FOR_FRAG \
    _Pragma("unroll") for (int nt2 = 0; nt2 < 2; ++nt2) \
    _Pragma("unroll") for (int i = 0; i < 4; ++i)

__global__ __launch_bounds__(1024, 4) void rnn_kernel(
    const u16* __restrict__ prep, const u16* __restrict__ w_t_,
    const u16* __restrict__ w_rh, const u16* __restrict__ w_zh,
    const u16* __restrict__ w_hh, float* __restrict__ out)
{
    __shared__ __align__(16) u16 hS[16 * SROW];        // h / ho / rh
    __shared__ __align__(16) u16 wbuf0[32 * 1024];     // 64KB chunk buf A
    __shared__ __align__(16) u16 wbuf1[32 * 1024];     // 64KB chunk buf B
    const int tid = threadIdx.x;
    const int lane = tid & 63;
    const int wave = tid >> 6;
    const int l15 = lane & 15, hi = lane >> 4;
    const int rx = l15 & 7;
    const int n0 = wave * 32;
    const long b0 = (long)blockIdx.x * 16;
    const int bo0 = (wave * 128 + (l15 >> 1) * 8
                     + ((hi + 4 * (l15 & 1)) ^ (l15 >> 1))) * 8;

    for (int i = tid * 8; i < 16 * SROW; i += 1024 * 8)
        *(short8*)(hS + i) = (short8)0;
    __syncthreads();

    const u16* pbase = prep + (long)blockIdx.x * (Tsz * 4 * 8192)
                       + wave * 512 + lane * 8;

#pragma unroll 1
    for (int t = 0; t < Tsz; ++t) {
        const u16* pt = pbase + (long)t * 4 * 8192;
        short8 po = ntload8(pt);

        // ---- stage A: ho = sigm(pre_o + h @ w_t^T)  [reads hS = h] ----
        f32x4 accO[2];
        accO[0] = f32x4{0,0,0,0}; accO[1] = f32x4{0,0,0,0};
        wpass_staged(accO, hS, w_t_, wbuf0, wbuf1, bo0, rx, l15, hi,
                     wave, lane);
        float hov[2][4];
        FOR_FRAG {
            float v = sigm(accO[nt2][i] + bf2f((u16)po[nt2 * 4 + i]));
            hov[nt2][i] = v;
        }
        __syncthreads();   // all waves done reading hS(=h)
        FOR_FRAG hS[swz(hi * 4 + i, n0 + nt2 * 16 + l15)] = f2bf(hov[nt2][i]);

        // ---- stage B: r,z = sigm(pre + ho @ w^T)  [reads hS = ho] ----
        short8 pr = ntload8(pt + 8192);
        short8 pz = ntload8(pt + 2 * 8192);
        f32x4 accR[2];
        accR[0] = f32x4{0,0,0,0}; accR[1] = f32x4{0,0,0,0};
        wpass_staged(accR, hS, w_rh, wbuf0, wbuf1, bo0, rx, l15, hi,
                     wave, lane);
        f32x4 accZ[2];
        accZ[0] = f32x4{0,0,0,0}; accZ[1] = f32x4{0,0,0,0};
        wpass_staged(accZ, hS, w_zh, wbuf0, wbuf1, bo0, rx, l15, hi,
                     wave, lane);
        float zv[2][4], rhv[2][4];
        FOR_FRAG {
            zv[nt2][i] = sigm(accZ[nt2][i] + bf2f((u16)pz[nt2 * 4 + i]));
            float rv = sigm(accR[nt2][i] + bf2f((u16)pr[nt2 * 4 + i]));
            rhv[nt2][i] = rv * hov[nt2][i];
        }
        __syncthreads();   // all waves done reading hS(=ho)
        FOR_FRAG hS[swz(hi * 4 + i, n0 + nt2 * 16 + l15)] = f2bf(rhv[nt2][i]);

        // ---- stage C: h~ = tanh(pre_h + rh @ w_hh^T)  [reads hS = rh] ----
        short8 ph = ntload8(pt + 3 * 8192);
        f32x4 accH[2];
        accH[0] = f32x4{0,0,0,0}; accH[1] = f32x4{0,0,0,0};
        wpass_staged(accH, hS, w_hh, wbuf0, wbuf1, bo0, rx, l15, hi,
                     wave, lane);
        __syncthreads();   // all waves done reading hS(=rh)
        FOR_FRAG {
            int row = hi * 4 + i, col = n0 + nt2 * 16 + l15;
            float htl = tanhf(accH[nt2][i] + bf2f((u16)ph[nt2 * 4 + i]));
            float z = zv[nt2][i];
            float hn = (1.0f - z) * hov[nt2][i] + z * htl;
            __builtin_nontemporal_store(
                hn, &out[((b0 + row) * Tsz + t) * (long)Hsz + col]);
            hS[swz(row, col)] = f2bf(hn);
        }
    }
}

extern "C" void kernel_launch(void* const* d_in, const int* in_sizes, int n_in,
                              void* d_out, int out_size, void* d_ws, size_t ws_size,
                              hipStream_t stream) {
    const float* x_f    = (const float*)d_in[0];
    const float* xw_f   = (const float*)d_in[1];
    const float* w_rx_f = (const float*)d_in[2];
    const float* w_rh_f = (const float*)d_in[3];
    const float* w_re_f = (const float*)d_in[4];
    const float* b_r    = (const float*)d_in[5];
    const float* w_zx_f = (const float*)d_in[6];
    const float* w_zh_f = (const float*)d_in[7];
    const float* w_ze_f = (const float*)d_in[8];
    const float* b_z    = (const float*)d_in[9];
    const float* w_hx_f = (const float*)d_in[10];
    const float* w_hh_f = (const float*)d_in[11];
    const float* b_h    = (const float*)d_in[12];
    const float* w_d_f  = (const float*)d_in[13];
    const float* w_w_f  = (const float*)d_in[14];
    const float* w_m_f  = (const float*)d_in[15];
    const float* w_t_f  = (const float*)d_in[16];
    const float* w_e_f  = (const float*)d_in[17];
    const float* b_e    = (const float*)d_in[18];
    float* out = (float*)d_out;

    char* ws = (char*)d_ws;
    size_t off = 0;
    auto alloc = [&](size_t bytes) {
        size_t o = off; off = (off + bytes + 255) & ~(size_t)255; return o;
    };
    const size_t nx  = (size_t)Msz * Isz;
    const size_t nxw = (size_t)Msz * Wsz;

    u16* x_bf  = (u16*)(ws + alloc(nx * 2));
    u16* xw_bf = (u16*)(ws + alloc(nxw * 2));
    u16* w_rx  = (u16*)(ws + alloc(Hsz * Isz * 2));
    u16* w_rh  = (u16*)(ws + alloc(Hsz * Hsz * 2));
    u16* w_re  = (u16*)(ws + alloc(Hsz * Hsz * 2));
    u16* w_zx  = (u16*)(ws + alloc(Hsz * Isz * 2));
    u16* w_zh  = (u16*)(ws + alloc(Hsz * Hsz * 2));
    u16* w_ze  = (u16*)(ws + alloc(Hsz * Hsz * 2));
    u16* w_hx  = (u16*)(ws + alloc(Hsz * Isz * 2));
    u16* w_hh  = (u16*)(ws + alloc(Hsz * Hsz * 2));
    u16* w_d   = (u16*)(ws + alloc(Hsz * Isz * 2));
    u16* w_w   = (u16*)(ws + alloc(Hsz * Isz * 2));
    u16* w_m   = (u16*)(ws + alloc(Hsz * Isz * 2));
    u16* w_t   = (u16*)(ws + alloc(Hsz * Hsz * 2));
    u16* w_e   = (u16*)(ws + alloc(Hsz * Wsz * 2));
    u16* e_bf  = (u16*)(ws + alloc((size_t)Msz * Hsz * 2));   // 96 MB [b*T+t]
    u16* prep  = (u16*)(ws + alloc((size_t)Msz * 2048 * 2));  // 384 MB permuted
    u16* zerobuf = (u16*)(ws + alloc(256));

    convert_big<<<(int)(nx / 1024), 256, 0, stream>>>(x_f, x_bf, (int)nx);
    convert_big<<<(int)(nxw / 1024), 256, 0, stream>>>(xw_f, xw_bf, (int)nxw);
    ConvTab tab;
    tab.d[0]  = { w_rx_f, w_rx, Hsz * Isz };
    tab.d[1]  = { w_rh_f, w_rh, Hsz * Hsz };
    tab.d[2]  = { w_re_f, w_re, Hsz * Hsz };
    tab.d[3]  = { w_zx_f, w_zx, Hsz * Isz };
    tab.d[4]  = { w_zh_f, w_zh, Hsz * Hsz };
    tab.d[5]  = { w_ze_f, w_ze, Hsz * Hsz };
    tab.d[6]  = { w_hx_f, w_hx, Hsz * Isz };
    tab.d[7]  = { w_hh_f, w_hh, Hsz * Hsz };
    tab.d[8]  = { w_d_f,  w_d,  Hsz * Isz };
    tab.d[9]  = { w_w_f,  w_w,  Hsz * Isz };
    tab.d[10] = { w_m_f,  w_m,  Hsz * Isz };
    tab.d[11] = { w_t_f,  w_t,  Hsz * Hsz };
    tab.d[12] = { w_e_f,  w_e,  Hsz * Wsz };
    convert_many<<<dim3(256, 13), 256, 0, stream>>>(tab);
    hipMemsetAsync(zerobuf, 0, 256, stream);

    // e = sigmoid(xw @ w_e^T + b_e)  [98304 x 512], layout [b*T+t]
    ekernel<<<dim3(Msz / 64, Hsz / 64), 256, 0, stream>>>(xw_bf, w_e, b_e, e_bf);

    // pre-pass: 1-D grid, XCD-stream swizzle
    prepass_kernel<<<Msz / 128 * 16, 256, 0, stream>>>(
        x_bf, e_bf, w_d, w_w, w_m, w_rx, w_re, w_zx, w_ze, w_hx,
        b_r, b_z, b_h, zerobuf, prep);

    // persistent recurrence: 256 blocks x 16 waves, K=64 staged chunks
    rnn_kernel<<<Bsz / 16, 1024, 0, stream>>>(prep, w_t, w_rh, w_zh, w_hh, out);
}